// Round 5
// baseline (43.711 us; speedup 1.0000x reference)
//
#include <hip/hip_runtime.h>

#define HH 512
#define WW 512
#define NB 4            // batch
#define NC 3            // channels
#define NK 33           // histogram grid points
#define SPC 0.0625f     // 2/32
#define REP 4           // global accumulator replicas
#define NREP 16         // LDS sub-histogram replicas
#define NCLS 7          // region-combination classes (lips|face<<1|eye<<2, 1..7)
#define CLS_SZ (NCLS*NC*NK)         // 693 = [class-1][channel][bin]
#define GRP_SZ (3*NC*NK)            // 297 = [region][channel][bin]
#define BBOX_CH 64
#define HIST_CH 128
#define NBLK_BBOX (2*NB*BBOX_CH)    // 512
#define NBLK_HIST (2*NB*HIST_CH)    // 1024

// workspace layout (4-byte words):
//   [0 .. 2048)        int4 bbp[512]  partial bboxes {ymin,ymax,xmin,xmax}
//   [2048]             uint ticket
//   [2056 .. +9504)    uint gcnt[REP][2][NB][297]
//   [GSUM .. +9504)    float gsum[REP][2][NB][297]
#define BBP_OFF    0
#define TICKET_OFF 2048
#define GCNT_OFF   2056
#define GCNT_SZ    (REP*2*NB*GRP_SZ)        // 9504
#define GSUM_OFF   (GCNT_OFF + GCNT_SZ)     // 11560
#define WS_TOTAL   (GSUM_OFF + GCNT_SZ)     // 21064 words (~84 KB)
#define ZERO_SZ    (WS_TOTAL - TICKET_OFF)  // 19016
#define ZERO_PER   ((ZERO_SZ + NBLK_BBOX - 1) / NBLK_BBOX)   // 38

__global__ __launch_bounds__(256) void k_bbox(const int* __restrict__ seg_gen,
                                              const int* __restrict__ seg_real,
                                              int* __restrict__ ws) {
    int bid = blockIdx.x, tid = (int)threadIdx.x;

    // cooperative zero of ticket + gcnt + gsum (plain stores; visible at kernel boundary)
    int zbase = TICKET_OFF + bid * ZERO_PER;
    for (int i = tid; i < ZERO_PER; i += 256) {
        int idx = zbase + i;
        if (idx < WS_TOTAL) ws[idx] = 0;
    }

    int map = bid / (NB * BBOX_CH);
    int rem = bid % (NB * BBOX_CH);
    int b = rem / BBOX_CH, chunk = rem % BBOX_CH;
    const int4* seg4 = (const int4*)((map == 0 ? seg_gen : seg_real) + b * HH * WW);
    int base4 = chunk * (4096 / 4);          // 1024 int4 per chunk

    int4 v[4];
    #pragma unroll
    for (int it = 0; it < 4; ++it) v[it] = seg4[base4 + it * 256 + tid];

    int ymin = HH, ymax = -1, xmin = WW, xmax = -1;
    #pragma unroll
    for (int it = 0; it < 4; ++it) {
        int p0 = (base4 + it * 256 + tid) * 4;
        int h = p0 >> 9, w0 = p0 & (WW - 1);
        int sv[4] = {v[it].x, v[it].y, v[it].z, v[it].w};
        #pragma unroll
        for (int j = 0; j < 4; ++j) {
            int s = sv[j];
            if (s == 4 || s == 5) {
                ymin = min(ymin, h); ymax = max(ymax, h);
                xmin = min(xmin, w0 + j); xmax = max(xmax, w0 + j);
            }
        }
    }
    __shared__ int sy0[256], sy1[256], sx0[256], sx1[256];
    sy0[tid] = ymin; sy1[tid] = ymax; sx0[tid] = xmin; sx1[tid] = xmax;
    __syncthreads();
    for (int off = 128; off > 0; off >>= 1) {
        if (tid < off) {
            sy0[tid] = min(sy0[tid], sy0[tid + off]);
            sy1[tid] = max(sy1[tid], sy1[tid + off]);
            sx0[tid] = min(sx0[tid], sx0[tid + off]);
            sx1[tid] = max(sx1[tid], sx1[tid + off]);
        }
        __syncthreads();
    }
    if (tid == 0)
        ((int4*)ws)[BBP_OFF / 4 + bid] = make_int4(sy0[0], sy1[0], sx0[0], sx1[0]);
}

__global__ __launch_bounds__(256) void k_hist(const float* __restrict__ gen,
                                              const float* __restrict__ realv,
                                              const int* __restrict__ seg_gen,
                                              const int* __restrict__ seg_real,
                                              int* __restrict__ ws,
                                              float* __restrict__ out) {
    int bid = blockIdx.x, tid = (int)threadIdx.x;
    int map = bid / (NB * HIST_CH);
    int rem = bid % (NB * HIST_CH);
    int b = rem / HIST_CH, chunk = rem % HIST_CH;
    const float* img = (map == 0 ? gen : realv);
    const int* seg = (map == 0 ? seg_gen : seg_real) + b * HH * WW;

    // LDS: class-histogram replicas (phase 1) aliased with finalize arrays (phase 2)
    __shared__ unsigned lh[NREP * CLS_SZ];   // 11088 u32 = 44.3 KB
    __shared__ int sbb[5];                   // ymin,ymax,xmin,xmax,has
    __shared__ int slast;

    for (int i = tid; i < NREP * CLS_SZ; i += 256) lh[i] = 0u;

    // reduce 64 partial bboxes for this (map,b) with a wave-0 shfl reduce
    if (tid < 64) {
        int4 v = ((const int4*)ws)[BBP_OFF / 4 + (map * NB + b) * BBOX_CH + tid];
        #pragma unroll
        for (int off = 32; off > 0; off >>= 1) {
            v.x = min(v.x, __shfl_xor(v.x, off));
            v.y = max(v.y, __shfl_xor(v.y, off));
            v.z = min(v.z, __shfl_xor(v.z, off));
            v.w = max(v.w, __shfl_xor(v.w, off));
        }
        if (tid == 0) {
            int ymin0 = v.x, ymax0 = v.y, xmin0 = v.z, xmax0 = v.w;
            int has = (ymax0 >= 0);
            int pady = (int)(0.15f * (float)(ymax0 - ymin0));
            int padx = (int)(0.15f * (float)(xmax0 - xmin0));
            int ymin = max(0, ymin0 - pady);
            int ymaxv = min(HH, ymax0 + pady);
            int xminv = max(0, xmin0 - padx);
            int xmaxv = min(WW, xmax0 + padx);
            ymaxv = min(HH - 1, ymaxv + pady);   // double-pad quirk
            xmaxv = min(WW - 1, xmaxv + padx);
            sbb[0] = ymin; sbb[1] = ymaxv; sbb[2] = xminv; sbb[3] = xmaxv; sbb[4] = has;
        }
    }
    __syncthreads();
    int bbym = sbb[0], bbyM = sbb[1], bbxm = sbb[2], bbxM = sbb[3], has = sbb[4];

    // ---- main pass: 2048 px/block, 8 px/thread, all loads hoisted ----
    // ONE packed atomic per (pixel, channel) into the pixel's region-class slot.
    unsigned* lhr = lh + (tid & (NREP - 1)) * CLS_SZ;
    int q0 = chunk * (2048 / 4) + tid;       // int4 index, group A
    int q1 = q0 + 256;                       // group B
    const int4* seg4 = (const int4*)seg;
    int4 sA = seg4[q0], sB = seg4[q1];
    const float4* i4 = (const float4*)img + ((size_t)(b * NC) << 16);
    float4 fA0 = i4[(0 << 16) + q0], fA1 = i4[(1 << 16) + q0], fA2 = i4[(2 << 16) + q0];
    float4 fB0 = i4[(0 << 16) + q1], fB1 = i4[(1 << 16) + q1], fB2 = i4[(2 << 16) + q1];

    #pragma unroll
    for (int g = 0; g < 2; ++g) {
        int p = (g == 0 ? q0 : q1) * 4;
        int4 s4 = (g == 0) ? sA : sB;
        float xs0[4], xs1[4], xs2[4];
        { float4 f = (g == 0) ? fA0 : fB0; xs0[0]=f.x; xs0[1]=f.y; xs0[2]=f.z; xs0[3]=f.w; }
        { float4 f = (g == 0) ? fA1 : fB1; xs1[0]=f.x; xs1[1]=f.y; xs1[2]=f.z; xs1[3]=f.w; }
        { float4 f = (g == 0) ? fA2 : fB2; xs2[0]=f.x; xs2[1]=f.y; xs2[2]=f.z; xs2[3]=f.w; }
        int h = p >> 9, w0 = p & (WW - 1);
        bool eyerow = has && (h >= bbym) && (h < bbyM);
        int sv[4] = {s4.x, s4.y, s4.z, s4.w};
        #pragma unroll
        for (int j = 0; j < 4; ++j) {
            int s = sv[j];
            int cls = (int)((s == 11) | (s == 12))
                    | ((int)(s == 1) << 1)
                    | ((int)(eyerow & ((w0 + j) >= bbxm) & ((w0 + j) < bbxM)) << 2);
            if (!cls) continue;
            unsigned* basep = lhr + (cls - 1) * (NC * NK);
            #pragma unroll
            for (int c = 0; c < NC; ++c) {
                float x = (c == 0) ? xs0[j] : (c == 1) ? xs1[j] : xs2[j];
                float t = (x + 1.0f) * 16.0f;
                int k0 = (int)t;
                k0 = min(max(k0, 0), NK - 1);
                float f = t - (float)k0;
                unsigned pk = 0x1000000u | (unsigned)(f * 4096.0f);
                atomicAdd(&basep[c * NK + k0], pk);
            }
        }
    }
    __syncthreads();

    // ---- flush A: reduce 16 replicas in place (column i owned by one thread) ----
    for (int i = tid; i < CLS_SZ; i += 256) {
        unsigned cnt = 0, fq = 0;
        #pragma unroll
        for (int r = 0; r < NREP; ++r) {
            unsigned v = lh[r * CLS_SZ + i];
            cnt += v >> 24;
            fq  += v & 0xFFFFFFu;
        }
        lh[i] = cnt;                  // class-combined counts
        lh[CLS_SZ + i] = fq;          // class-combined frac sums (quantized)
    }
    __syncthreads();

    // ---- flush B: classes -> regions, global atomics (REP-spread) ----
    int rep = bid & (REP - 1);
    unsigned* gcnt = (unsigned*)ws + GCNT_OFF + ((rep * 2 + map) * NB + b) * GRP_SZ;
    float*    gsum = (float*)ws + GSUM_OFF + ((rep * 2 + map) * NB + b) * GRP_SZ;
    // region r includes classes whose bit r is set
    const int rcls0[3] = {1, 2, 4};   // minimal class containing region bit
    for (int i = tid; i < GRP_SZ; i += 256) {
        int r = i / (NC * NK);
        int rest = i % (NC * NK);
        unsigned cnt = 0, fq = 0;
        #pragma unroll
        for (int m = 1; m < 8; ++m) {
            if (m & rcls0[r]) {
                cnt += lh[(m - 1) * (NC * NK) + rest];
                fq  += lh[CLS_SZ + (m - 1) * (NC * NK) + rest];
            }
        }
        if (cnt) {
            atomicAdd(&gcnt[i], cnt);
            atomicAdd(&gsum[i], (float)fq * (1.0f / 4096.0f));
        }
    }
    __syncthreads();          // drains flush atomics before ticket

    // ---- last-block finalize ----
    if (tid == 0) {
        __threadfence();
        unsigned t = atomicAdd((unsigned*)ws + TICKET_OFF, 1u);
        slast = (t == NBLK_HIST - 1);
    }
    __syncthreads();
    if (!slast) return;
    __threadfence();          // acquire

    unsigned* smem = lh;
    float* sC   = (float*)smem;              // [2376]
    float* sF   = sC + 2 * NB * GRP_SZ;      // [2376]
    float* sNum = sF + 2 * NB * GRP_SZ;      // [2376]
    int*   sN   = (int*)(smem + 7128);       // [24]
    float* sS   = (float*)(smem + 7152);     // [72]
    double* sRed = (double*)(smem + 7224);   // [256] doubles -> words 7224..7736

    const unsigned* gcntAll = (const unsigned*)ws + GCNT_OFF;
    const float*    gsumAll = (const float*)ws + GSUM_OFF;
    const int NITEM = 2 * NB * GRP_SZ;       // 2376
    for (int i = tid; i < NITEM; i += 256) {
        int mp = i / (NB * GRP_SZ);
        int r2 = i % (NB * GRP_SZ);
        int b2 = r2 / GRP_SZ, idx = r2 % GRP_SZ;
        float C = 0.0f, F = 0.0f;
        #pragma unroll
        for (int rp = 0; rp < REP; ++rp) {
            int off = ((rp * 2 + mp) * NB + b2) * GRP_SZ + idx;
            C += (float)gcntAll[off];
            F += gsumAll[off];
        }
        sC[i] = C; sF[i] = F;
    }
    __syncthreads();
    if (tid < 24) {           // N[map][b][r] from channel-0 counts
        int mp = tid / 12, b2 = (tid / 3) % NB, r = tid % 3;
        const float* p = sC + (mp * NB + b2) * GRP_SZ + r * (NC * NK);
        float n = 0.0f;
        for (int k = 0; k < NK; ++k) n += p[k];
        sN[tid] = (int)(n + 0.5f);
    }
    for (int i = tid; i < NITEM; i += 256) {
        int k = i % NK;
        float fp = (k > 0) ? sF[i - 1] : 0.0f;
        sNum[i] = fmaxf(SPC * ((sC[i] - sF[i]) + fp), 0.0f);
    }
    __syncthreads();
    if (tid < 72) {
        float s = 0.0f;
        const float* p = sNum + tid * NK;
        for (int k = 0; k < NK; ++k) s += p[k];
        sS[tid] = s;
    }
    __syncthreads();
    double acc = 0.0;
    for (int j = tid; j < NB * GRP_SZ; j += 256) {   // 1188 (b, r, c, k)
        int b2 = j / GRP_SZ, idx = j % GRP_SZ;
        int r = idx / (NC * NK);
        int c = (idx / NK) % NC;
        int ng = sN[b2 * 3 + r];
        int nr = sN[12 + b2 * 3 + r];
        if (ng > 0 && nr > 0) {
            int g = b2 * 9 + r * 3 + c;              // sS group index within a map
            float dg = (float)ng * sS[g];
            float dr = (float)nr * sS[36 + g];
            dg = (dg > 0.0f) ? dg : 1.0f;
            dr = (dr > 0.0f) ? dr : 1.0f;
            double d = fabs((double)(sNum[j] / dg) - (double)(sNum[NB * GRP_SZ + j] / dr));
            acc += ((r == 1) ? 0.1 : 1.0) * d;
        }
    }
    sRed[tid] = acc;
    __syncthreads();
    for (int off = 128; off > 0; off >>= 1) {
        if (tid < off) sRed[tid] += sRed[tid + off];
        __syncthreads();
    }
    if (tid == 0) out[0] = (float)(sRed[0] / (double)NK / (double)(NB * NC * 3));
}

extern "C" void kernel_launch(void* const* d_in, const int* in_sizes, int n_in,
                              void* d_out, int out_size, void* d_ws, size_t ws_size,
                              hipStream_t stream) {
    const float* gen    = (const float*)d_in[0];
    const float* realv  = (const float*)d_in[1];
    const int* seg_gen  = (const int*)d_in[2];
    const int* seg_real = (const int*)d_in[3];
    int* wsi = (int*)d_ws;

    k_bbox<<<dim3(NBLK_BBOX), dim3(256), 0, stream>>>(seg_gen, seg_real, wsi);
    k_hist<<<dim3(NBLK_HIST), dim3(256), 0, stream>>>(gen, realv, seg_gen, seg_real,
                                                      wsi, (float*)d_out);
}

// Round 6
// 28.606 us; speedup vs baseline: 1.5280x; 1.5280x over previous
//
#include <hip/hip_runtime.h>

#define HH 512
#define WW 512
#define NB 4            // batch
#define NC 3            // channels
#define NK 33           // histogram grid points
#define SPC 0.0625f     // 2/32
#define REP 4           // global accumulator replicas
#define NREP 16         // LDS sub-histogram replicas
#define NCLS 7          // region-combination classes (lips|face<<1|eye<<2, 1..7)
#define CLS_SZ (NCLS*NC*NK)         // 693 = [class-1][channel][bin]
#define GRP_SZ (3*NC*NK)            // 297 = [region][channel][bin]
#define BBOX_CH 64
#define HIST_CH 128
#define NBLK_BBOX (2*NB*BBOX_CH)    // 512
#define NBLK_HIST (2*NB*HIST_CH)    // 1024

// workspace layout (4-byte words):
//   [0 .. 2048)        int4 bbp[512]  partial bboxes {ymin,ymax,xmin,xmax}
//   [2048]             (unused)
//   [2056 .. +9504)    uint gcnt[REP][2][NB][297]
//   [GSUM .. +9504)    float gsum[REP][2][NB][297]
#define BBP_OFF    0
#define GCNT_OFF   2056
#define GCNT_SZ    (REP*2*NB*GRP_SZ)        // 9504
#define GSUM_OFF   (GCNT_OFF + GCNT_SZ)     // 11560
#define WS_TOTAL   (GSUM_OFF + GCNT_SZ)     // 21064 words (~84 KB)
#define ZERO_BASE  2048
#define ZERO_SZ    (WS_TOTAL - ZERO_BASE)   // 19016
#define ZERO_PER   ((ZERO_SZ + NBLK_BBOX - 1) / NBLK_BBOX)   // 38

__global__ __launch_bounds__(256) void k_bbox(const int* __restrict__ seg_gen,
                                              const int* __restrict__ seg_real,
                                              int* __restrict__ ws) {
    int bid = blockIdx.x, tid = (int)threadIdx.x;

    // cooperative zero of gcnt + gsum (plain stores; visible at kernel boundary)
    int zbase = ZERO_BASE + bid * ZERO_PER;
    for (int i = tid; i < ZERO_PER; i += 256) {
        int idx = zbase + i;
        if (idx < WS_TOTAL) ws[idx] = 0;
    }

    int map = bid / (NB * BBOX_CH);
    int rem = bid % (NB * BBOX_CH);
    int b = rem / BBOX_CH, chunk = rem % BBOX_CH;
    const int4* seg4 = (const int4*)((map == 0 ? seg_gen : seg_real) + b * HH * WW);
    int base4 = chunk * (4096 / 4);          // 1024 int4 per chunk

    int4 v[4];
    #pragma unroll
    for (int it = 0; it < 4; ++it) v[it] = seg4[base4 + it * 256 + tid];

    int ymin = HH, ymax = -1, xmin = WW, xmax = -1;
    #pragma unroll
    for (int it = 0; it < 4; ++it) {
        int p0 = (base4 + it * 256 + tid) * 4;
        int h = p0 >> 9, w0 = p0 & (WW - 1);
        int sv[4] = {v[it].x, v[it].y, v[it].z, v[it].w};
        #pragma unroll
        for (int j = 0; j < 4; ++j) {
            int s = sv[j];
            if (s == 4 || s == 5) {
                ymin = min(ymin, h); ymax = max(ymax, h);
                xmin = min(xmin, w0 + j); xmax = max(xmax, w0 + j);
            }
        }
    }
    __shared__ int sy0[256], sy1[256], sx0[256], sx1[256];
    sy0[tid] = ymin; sy1[tid] = ymax; sx0[tid] = xmin; sx1[tid] = xmax;
    __syncthreads();
    for (int off = 128; off > 0; off >>= 1) {
        if (tid < off) {
            sy0[tid] = min(sy0[tid], sy0[tid + off]);
            sy1[tid] = max(sy1[tid], sy1[tid + off]);
            sx0[tid] = min(sx0[tid], sx0[tid + off]);
            sx1[tid] = max(sx1[tid], sx1[tid + off]);
        }
        __syncthreads();
    }
    if (tid == 0)
        ((int4*)ws)[BBP_OFF / 4 + bid] = make_int4(sy0[0], sy1[0], sx0[0], sx1[0]);
}

__global__ __launch_bounds__(256) void k_hist(const float* __restrict__ gen,
                                              const float* __restrict__ realv,
                                              const int* __restrict__ seg_gen,
                                              const int* __restrict__ seg_real,
                                              int* __restrict__ ws) {
    int bid = blockIdx.x, tid = (int)threadIdx.x;
    int map = bid / (NB * HIST_CH);
    int rem = bid % (NB * HIST_CH);
    int b = rem / HIST_CH, chunk = rem % HIST_CH;
    const float* img = (map == 0 ? gen : realv);
    const int* seg = (map == 0 ? seg_gen : seg_real) + b * HH * WW;

    __shared__ unsigned lh[NREP * CLS_SZ];   // 11088 u32 = 44.3 KB
    __shared__ int sbb[5];                   // ymin,ymax,xmin,xmax,has

    for (int i = tid; i < NREP * CLS_SZ; i += 256) lh[i] = 0u;

    // reduce 64 partial bboxes for this (map,b) with a wave-0 shfl reduce
    if (tid < 64) {
        int4 v = ((const int4*)ws)[BBP_OFF / 4 + (map * NB + b) * BBOX_CH + tid];
        #pragma unroll
        for (int off = 32; off > 0; off >>= 1) {
            v.x = min(v.x, __shfl_xor(v.x, off));
            v.y = max(v.y, __shfl_xor(v.y, off));
            v.z = min(v.z, __shfl_xor(v.z, off));
            v.w = max(v.w, __shfl_xor(v.w, off));
        }
        if (tid == 0) {
            int ymin0 = v.x, ymax0 = v.y, xmin0 = v.z, xmax0 = v.w;
            int has = (ymax0 >= 0);
            int pady = (int)(0.15f * (float)(ymax0 - ymin0));
            int padx = (int)(0.15f * (float)(xmax0 - xmin0));
            int ymin = max(0, ymin0 - pady);
            int ymaxv = min(HH, ymax0 + pady);
            int xminv = max(0, xmin0 - padx);
            int xmaxv = min(WW, xmax0 + padx);
            ymaxv = min(HH - 1, ymaxv + pady);   // double-pad quirk
            xmaxv = min(WW - 1, xmaxv + padx);
            sbb[0] = ymin; sbb[1] = ymaxv; sbb[2] = xminv; sbb[3] = xmaxv; sbb[4] = has;
        }
    }
    __syncthreads();
    int bbym = sbb[0], bbyM = sbb[1], bbxm = sbb[2], bbxM = sbb[3], has = sbb[4];

    // ---- main pass: 2048 px/block, 8 px/thread, all loads hoisted ----
    unsigned* lhr = lh + (tid & (NREP - 1)) * CLS_SZ;
    int q0 = chunk * (2048 / 4) + tid;       // int4 index, group A
    int q1 = q0 + 256;                       // group B
    const int4* seg4 = (const int4*)seg;
    int4 sA = seg4[q0], sB = seg4[q1];
    const float4* i4 = (const float4*)img + ((size_t)(b * NC) << 16);
    float4 fA0 = i4[(0 << 16) + q0], fA1 = i4[(1 << 16) + q0], fA2 = i4[(2 << 16) + q0];
    float4 fB0 = i4[(0 << 16) + q1], fB1 = i4[(1 << 16) + q1], fB2 = i4[(2 << 16) + q1];

    #pragma unroll
    for (int g = 0; g < 2; ++g) {
        int p = (g == 0 ? q0 : q1) * 4;
        int4 s4 = (g == 0) ? sA : sB;
        float xs0[4], xs1[4], xs2[4];
        { float4 f = (g == 0) ? fA0 : fB0; xs0[0]=f.x; xs0[1]=f.y; xs0[2]=f.z; xs0[3]=f.w; }
        { float4 f = (g == 0) ? fA1 : fB1; xs1[0]=f.x; xs1[1]=f.y; xs1[2]=f.z; xs1[3]=f.w; }
        { float4 f = (g == 0) ? fA2 : fB2; xs2[0]=f.x; xs2[1]=f.y; xs2[2]=f.z; xs2[3]=f.w; }
        int h = p >> 9, w0 = p & (WW - 1);
        bool eyerow = has && (h >= bbym) && (h < bbyM);
        int sv[4] = {s4.x, s4.y, s4.z, s4.w};
        #pragma unroll
        for (int j = 0; j < 4; ++j) {
            int s = sv[j];
            int cls = (int)((s == 11) | (s == 12))
                    | ((int)(s == 1) << 1)
                    | ((int)(eyerow & ((w0 + j) >= bbxm) & ((w0 + j) < bbxM)) << 2);
            if (!cls) continue;
            unsigned* basep = lhr + (cls - 1) * (NC * NK);
            #pragma unroll
            for (int c = 0; c < NC; ++c) {
                float x = (c == 0) ? xs0[j] : (c == 1) ? xs1[j] : xs2[j];
                float t = (x + 1.0f) * 16.0f;
                int k0 = (int)t;
                k0 = min(max(k0, 0), NK - 1);
                float f = t - (float)k0;
                unsigned pk = 0x1000000u | (unsigned)(f * 4096.0f);
                atomicAdd(&basep[c * NK + k0], pk);
            }
        }
    }
    __syncthreads();

    // ---- flush A: reduce 16 replicas in place ----
    for (int i = tid; i < CLS_SZ; i += 256) {
        unsigned cnt = 0, fq = 0;
        #pragma unroll
        for (int r = 0; r < NREP; ++r) {
            unsigned v = lh[r * CLS_SZ + i];
            cnt += v >> 24;
            fq  += v & 0xFFFFFFu;
        }
        lh[i] = cnt;
        lh[CLS_SZ + i] = fq;
    }
    __syncthreads();

    // ---- flush B: classes -> regions, global atomics (REP-spread) ----
    int rep = bid & (REP - 1);
    unsigned* gcnt = (unsigned*)ws + GCNT_OFF + ((rep * 2 + map) * NB + b) * GRP_SZ;
    float*    gsum = (float*)ws + GSUM_OFF + ((rep * 2 + map) * NB + b) * GRP_SZ;
    const int rcls0[3] = {1, 2, 4};
    for (int i = tid; i < GRP_SZ; i += 256) {
        int r = i / (NC * NK);
        int rest = i % (NC * NK);
        unsigned cnt = 0, fq = 0;
        #pragma unroll
        for (int m = 1; m < 8; ++m) {
            if (m & rcls0[r]) {
                cnt += lh[(m - 1) * (NC * NK) + rest];
                fq  += lh[CLS_SZ + (m - 1) * (NC * NK) + rest];
            }
        }
        if (cnt) {
            atomicAdd(&gcnt[i], cnt);
            atomicAdd(&gsum[i], (float)fq * (1.0f / 4096.0f));
        }
    }
}

#define NITEM (2 * NB * GRP_SZ)   // 2376
__global__ __launch_bounds__(1024) void k_final(const unsigned* __restrict__ wsu,
                                                const float* __restrict__ wsf,
                                                float* __restrict__ out) {
    int tid = (int)threadIdx.x;   // 1024 threads
    __shared__ float sC[NITEM], sF[NITEM], sNum[NITEM];
    __shared__ int   sN[2 * NB * 3];      // 24
    __shared__ float sS[2 * NB * NC * 3]; // 72
    __shared__ double sRed[1024];

    const unsigned* gcntAll = wsu + GCNT_OFF;
    const float*    gsumAll = wsf + GSUM_OFF;
    for (int i = tid; i < NITEM; i += 1024) {
        int mp = i / (NB * GRP_SZ);
        int r2 = i % (NB * GRP_SZ);
        int b2 = r2 / GRP_SZ, idx = r2 % GRP_SZ;
        float C = 0.0f, F = 0.0f;
        #pragma unroll
        for (int rp = 0; rp < REP; ++rp) {
            int off = ((rp * 2 + mp) * NB + b2) * GRP_SZ + idx;
            C += (float)gcntAll[off];
            F += gsumAll[off];
        }
        sC[i] = C; sF[i] = F;
    }
    __syncthreads();
    if (tid < 24) {           // N[map][b][r] from channel-0 counts
        int mp = tid / 12, b2 = (tid / 3) % NB, r = tid % 3;
        const float* p = sC + (mp * NB + b2) * GRP_SZ + r * (NC * NK);
        float n = 0.0f;
        for (int k = 0; k < NK; ++k) n += p[k];
        sN[tid] = (int)(n + 0.5f);
    }
    for (int i = tid; i < NITEM; i += 1024) {
        int k = i % NK;
        float fp = (k > 0) ? sF[i - 1] : 0.0f;
        sNum[i] = fmaxf(SPC * ((sC[i] - sF[i]) + fp), 0.0f);
    }
    __syncthreads();
    if (tid < 72) {
        float s = 0.0f;
        const float* p = sNum + tid * NK;
        for (int k = 0; k < NK; ++k) s += p[k];
        sS[tid] = s;
    }
    __syncthreads();
    double acc = 0.0;
    for (int j = tid; j < NB * GRP_SZ; j += 1024) {   // 1188 (b, r, c, k)
        int b2 = j / GRP_SZ, idx = j % GRP_SZ;
        int r = idx / (NC * NK);
        int c = (idx / NK) % NC;
        int ng = sN[b2 * 3 + r];
        int nr = sN[12 + b2 * 3 + r];
        if (ng > 0 && nr > 0) {
            int g = b2 * 9 + r * 3 + c;
            float dg = (float)ng * sS[g];
            float dr = (float)nr * sS[36 + g];
            dg = (dg > 0.0f) ? dg : 1.0f;
            dr = (dr > 0.0f) ? dr : 1.0f;
            double d = fabs((double)(sNum[j] / dg) - (double)(sNum[NB * GRP_SZ + j] / dr));
            acc += ((r == 1) ? 0.1 : 1.0) * d;
        }
    }
    sRed[tid] = acc;
    __syncthreads();
    for (int off = 512; off > 0; off >>= 1) {
        if (tid < off) sRed[tid] += sRed[tid + off];
        __syncthreads();
    }
    if (tid == 0) out[0] = (float)(sRed[0] / (double)NK / (double)(NB * NC * 3));
}

extern "C" void kernel_launch(void* const* d_in, const int* in_sizes, int n_in,
                              void* d_out, int out_size, void* d_ws, size_t ws_size,
                              hipStream_t stream) {
    const float* gen    = (const float*)d_in[0];
    const float* realv  = (const float*)d_in[1];
    const int* seg_gen  = (const int*)d_in[2];
    const int* seg_real = (const int*)d_in[3];
    int* wsi = (int*)d_ws;

    k_bbox <<<dim3(NBLK_BBOX), dim3(256),  0, stream>>>(seg_gen, seg_real, wsi);
    k_hist <<<dim3(NBLK_HIST), dim3(256),  0, stream>>>(gen, realv, seg_gen, seg_real, wsi);
    k_final<<<dim3(1),         dim3(1024), 0, stream>>>((const unsigned*)d_ws,
                                                        (const float*)d_ws,
                                                        (float*)d_out);
}